// Round 8
// baseline (316.789 us; speedup 1.0000x reference)
//
#include <hip/hip_runtime.h>

#define NUM_EMB 1024
#define EMB_DIM 256
#define NPIX    32768      // 32 * 32 * 32
#define HW      1024       // 32*32 spatial per batch
#define ZQ_ELEMS 8388608   // 32*256*32*32

// ws layout (bytes):
//   [0..8)                  double loss_accum
//   [8..8+4096)             float  tnorm[1024]
//   [8192..+131072)         float  snorm[32768]
//   [139264..+262144)       u64    keys[32768]  (argmin: (d_bits<<32)|idx)
//   [401408..+1028)         u32    tickets[257] (256 pixel-tile + 1 final)
//   [403456..+1572864)      u16    EB: e B-fragment planes [3][32][8][2][2][32][8]
#define WS_TNORM 8
#define WS_SNORM 8192
#define WS_KEYS  139264
#define WS_TICK  401408
#define WS_EB    403456

typedef unsigned long long u64;
typedef unsigned int u32;
typedef unsigned short u16;

typedef __bf16 bf16x8 __attribute__((ext_vector_type(8)));
typedef float f32x16 __attribute__((ext_vector_type(16)));
typedef u16 u16x8 __attribute__((ext_vector_type(8)));

// B-fragment-ordered e-planes: lane (hi,cl) of a wave reads 16B contiguous;
// 64 lanes = 1KB coalesced chunk per (p, g=code>>5, kt, ks).
__device__ __forceinline__ size_t eb_idx(int p, int g, int kt, int ks, int hi,
                                         int cl) {
  return ((((((size_t)p * 32 + g) * 8 + kt) * 2 + ks) * 2 + hi) * 32 + cl) * 8;
}

// ---- numpy pairwise_sum replica over 128 squared terms, stride between terms ----
__device__ __forceinline__ float pw128_sq(const float* x, int stride) {
  float r[8];
#pragma unroll
  for (int j = 0; j < 8; ++j) {
    float v = x[(size_t)j * stride];
    r[j] = __fmul_rn(v, v);
  }
  for (int i = 8; i < 128; i += 8) {
#pragma unroll
    for (int j = 0; j < 8; ++j) {
      float v = x[(size_t)(i + j) * stride];
      r[j] = __fadd_rn(r[j], __fmul_rn(v, v));
    }
  }
  float s01 = __fadd_rn(r[0], r[1]);
  float s23 = __fadd_rn(r[2], r[3]);
  float s45 = __fadd_rn(r[4], r[5]);
  float s67 = __fadd_rn(r[6], r[7]);
  return __fadd_rn(__fadd_rn(s01, s23), __fadd_rn(s45, s67));
}

// 3-way bf16 split: x = hf + mf + lf + eps, eps ~ 2^-26 |x|. Sterbenz-exact residuals.
__device__ __forceinline__ void split3(float x, u16& h, u16& m, u16& l) {
  u32 u = __float_as_uint(x);
  u16 hb = (u16)((u + 0x7fffu + ((u >> 16) & 1u)) >> 16);
  float hf = __uint_as_float((u32)hb << 16);
  float r1 = x - hf;                       // exact
  u32 u1 = __float_as_uint(r1);
  u16 mb = (u16)((u1 + 0x7fffu + ((u1 >> 16) & 1u)) >> 16);
  float mf = __uint_as_float((u32)mb << 16);
  float r2 = r1 - mf;                      // exact
  u32 u2 = __float_as_uint(r2);
  u16 lb = (u16)((u2 + 0x7fffu + ((u2 >> 16) & 1u)) >> 16);
  h = hb; m = mb; l = lb;
}

__device__ __forceinline__ u64 shfl_xor_u64(u64 v, int msk) {
  const u32 lo = __shfl_xor((u32)v, msk, 64);
  const u32 hi = __shfl_xor((u32)(v >> 32), msk, 64);
  return ((u64)hi << 32) | lo;
}

// ---- prep: keys=~0, loss=0, tickets=0, snorm (blk 0..127);
//      tnorm + e-split into B-frag layout (blk 128..131) ----
__global__ __launch_bounds__(256) void vq_prep_kernel(
    const float* __restrict__ z, const float* __restrict__ emb,
    float* __restrict__ tnorm, float* __restrict__ snorm,
    u64* __restrict__ keys, double* __restrict__ loss_accum,
    u32* __restrict__ tickets, u16* __restrict__ EB) {
  const int gid = blockIdx.x * 256 + threadIdx.x;
  if (gid == 0) *loss_accum = 0.0;
  if (gid < NPIX) {
    keys[gid] = ~0ull;
    const int b = gid >> 10, hw = gid & 1023;
    const float* base = z + (size_t)b * (EMB_DIM * HW) + hw;
    snorm[gid] = __fadd_rn(pw128_sq(base, HW), pw128_sq(base + (size_t)128 * HW, HW));
  } else {
    const int k = gid - NPIX;
    if (k < NUM_EMB) {
      if (k < 257) tickets[k] = 0u;
      const float* row = emb + (size_t)k * EMB_DIM;
      tnorm[k] = __fadd_rn(pw128_sq(row, 1), pw128_sq(row + 128, 1));
      const int g = k >> 5, cl = k & 31;
      for (int c = 0; c < EMB_DIM; c += 8) {
        u16x8 vh, vm, vl;
#pragma unroll
        for (int j = 0; j < 8; ++j) {
          u16 h_, m_, l_;
          split3(row[c + j], h_, m_, l_);
          vh[j] = h_; vm[j] = m_; vl[j] = l_;
        }
        const int kt = c >> 5, ks = (c >> 4) & 1, hi = (c >> 3) & 1;
        *(u16x8*)(EB + eb_idx(0, g, kt, ks, hi, cl)) = vh;
        *(u16x8*)(EB + eb_idx(1, g, kt, ks, hi, cl)) = vm;
        *(u16x8*)(EB + eb_idx(2, g, kt, ks, hi, cl)) = vl;
      }
    }
  }
}

// ---- main: 128 px x 128 codes per block, 32x32x16 MFMA.
// z staged in LDS (80B rows — measured conflict-free in R6); e read directly
// from L2-resident B-fragment-ordered planes (no e LDS, no e barriers).
// Outputs fused: 8th block per pixel-tile gathers z_q / idx / loss.
// logical bid: pt = bid>>3, nt = bid&7; XCD swizzle: h -> (h&7)*256 + (h>>3)
__global__ __launch_bounds__(256, 3) void vq_main_kernel(
    const float* __restrict__ z, const float* __restrict__ emb,
    const u16* __restrict__ EB,
    const float* __restrict__ tnorm, const float* __restrict__ snorm,
    u64* __restrict__ keys, double* __restrict__ loss_accum,
    u32* __restrict__ tickets, float* __restrict__ out,
    float* __restrict__ out_idx_f, float* __restrict__ out_loss) {
  __shared__ __align__(16) u16 zs[3][128][40];   // 30720 B, 80B rows
  __shared__ u64 part[128][2];                    // argmin combine / loss reduce
  __shared__ u32 flag;

  const int t   = threadIdx.x;
  const int hb  = blockIdx.x;
  const int bid = (hb & 7) * 256 + (hb >> 3);
  const int pt  = bid >> 3;
  const int ntb = bid & 7;
  const int m0  = pt * 128;
  const int n0  = ntb * 128;
  const int b   = m0 >> 10;
  const int hw0 = m0 & 1023;
  const float* zbase = z + (size_t)b * (EMB_DIM * HW) + hw0;

  const int l    = t & 63;
  const int wid  = t >> 6;
  const int wpx0 = (wid >> 1) * 64;   // wave pixel base within tile
  const int wcb  = (wid & 1) * 64;    // wave code base within tile
  const int cl   = l & 31;            // frag row/col lane
  const int hi   = l >> 5;            // k-octet select
  const int gb   = ntb * 4 + (wid & 1) * 2;   // EB g-base for this wave

  // staging: thread owns pixel sr, k-half skh (16 k's, two 16B chunks)
  const int sr  = t & 127;
  const int skh = (t >> 7) * 16;

  float gz[16];
#pragma unroll
  for (int j = 0; j < 16; ++j)
    gz[j] = zbase[(size_t)(skh + j) * HW + sr];

  f32x16 acc[2][2];
#pragma unroll
  for (int i = 0; i < 2; ++i)
#pragma unroll
    for (int j = 0; j < 2; ++j)
#pragma unroll
      for (int r = 0; r < 16; ++r) acc[i][j][r] = 0.0f;

  for (int kt = 0; kt < 8; ++kt) {
    // ---- B-frag loads for this kt (global->reg, L2-resident, no LDS hazard;
    //      issued early so latency hides under split3 + staging + barrier) ----
    bf16x8 bf[3][2][2];
#pragma unroll
    for (int p = 0; p < 3; ++p)
#pragma unroll
      for (int nn = 0; nn < 2; ++nn)
#pragma unroll
        for (int ks = 0; ks < 2; ++ks)
          bf[p][nn][ks] =
              *(const bf16x8*)(EB + eb_idx(p, gb + nn, kt, ks, hi, cl));

    // ---- split z + conflict-free b128 LDS writes (verified pattern) ----
#pragma unroll
    for (int c = 0; c < 2; ++c) {
      u16x8 vh, vm, vl;
#pragma unroll
      for (int j = 0; j < 8; ++j) {
        u16 h_, m_, l_;
        split3(gz[c * 8 + j], h_, m_, l_);
        vh[j] = h_; vm[j] = m_; vl[j] = l_;
      }
      *(u16x8*)&zs[0][sr][skh + c * 8] = vh;
      *(u16x8*)&zs[1][sr][skh + c * 8] = vm;
      *(u16x8*)&zs[2][sr][skh + c * 8] = vl;
    }
    // ---- prefetch next z tile ----
    if (kt < 7) {
      const int kb = (kt + 1) * 32;
#pragma unroll
      for (int j = 0; j < 16; ++j)
        gz[j] = zbase[(size_t)(kb + skh + j) * HW + sr];
    }
    __syncthreads();

#pragma unroll
    for (int ks = 0; ks < 2; ++ks) {
      bf16x8 af[3][2];
#pragma unroll
      for (int p = 0; p < 3; ++p)
#pragma unroll
        for (int mt = 0; mt < 2; ++mt)
          af[p][mt] =
              *(const bf16x8*)&zs[p][wpx0 + mt * 32 + cl][ks * 16 + hi * 8];
      // 6 split-product planes: hh, hm, mh, mm, hl, lh
#define PROD(PA, PB)                                                          \
      _Pragma("unroll")                                                       \
      for (int mt = 0; mt < 2; ++mt) {                                        \
        _Pragma("unroll")                                                     \
        for (int nn = 0; nn < 2; ++nn)                                        \
          acc[mt][nn] = __builtin_amdgcn_mfma_f32_32x32x16_bf16(              \
              af[PA][mt], bf[PB][nn][ks], acc[mt][nn], 0, 0, 0);              \
      }
      PROD(0, 0)
      PROD(0, 1)
      PROD(1, 0)
      PROD(1, 1)
      PROD(0, 2)
      PROD(2, 0)
#undef PROD
    }
    __syncthreads();
  }

  // ---- epilogue: d = fl(fl(s+t) - 2m); argmin via u64 keys ----
  // C layout (validated R6/R7): col = cl (code), row = (reg&3)+8*(reg>>2)+4*hi
  const float tv0 = tnorm[n0 + wcb + cl];
  const float tv1 = tnorm[n0 + wcb + 32 + cl];
  u64 bk[2][16];
#pragma unroll
  for (int mt = 0; mt < 2; ++mt)
#pragma unroll
    for (int reg = 0; reg < 16; ++reg) {
      const int row = wpx0 + mt * 32 + (reg & 3) + 8 * (reg >> 2) + 4 * hi;
      const float s = snorm[m0 + row];
      const float d0 = __fsub_rn(__fadd_rn(s, tv0), 2.0f * acc[mt][0][reg]);
      const float d1 = __fsub_rn(__fadd_rn(s, tv1), 2.0f * acc[mt][1][reg]);
      const u64 k0 = ((u64)__float_as_uint(d0) << 32) | (u32)(n0 + wcb + cl);
      const u64 k1 =
          ((u64)__float_as_uint(d1) << 32) | (u32)(n0 + wcb + 32 + cl);
      bk[mt][reg] = k0 < k1 ? k0 : k1;
    }
#pragma unroll
  for (int off = 1; off < 32; off <<= 1) {
#pragma unroll
    for (int mt = 0; mt < 2; ++mt)
#pragma unroll
      for (int reg = 0; reg < 16; ++reg) {
        const u64 o = shfl_xor_u64(bk[mt][reg], off);
        if (o < bk[mt][reg]) bk[mt][reg] = o;
      }
  }

  if (cl == 0) {
#pragma unroll
    for (int mt = 0; mt < 2; ++mt)
#pragma unroll
      for (int reg = 0; reg < 16; ++reg) {
        const int row = wpx0 + mt * 32 + (reg & 3) + 8 * (reg >> 2) + 4 * hi;
        part[row][wid & 1] = bk[mt][reg];
      }
  }
  __syncthreads();
  if (t < 128) {
    const u64 a = part[t][0], c = part[t][1];
    atomicMin(&keys[m0 + t], a < c ? a : c);
  }
  __syncthreads();   // drains the atomicMin vmem ops for all threads

  // ---- ticket: 8th block of this pixel-tile produces the outputs ----
  if (t == 0) {
    __threadfence();
    flag = (atomicAdd(&tickets[pt], 1u) == 7u) ? 1u : 0u;
  }
  __syncthreads();
  if (flag) {
    __threadfence();
    const int m  = t & 127;
    const int c0 = t >> 7;
    const int idx = (int)(u32)(keys[m0 + m] & 0xffffffffu);
    if (c0 == 0) out_idx_f[m0 + m] = (float)idx;
    const float* er = emb + (size_t)idx * EMB_DIM;
    const float* zb = zbase + m;
    float*       ob = out + (size_t)b * (EMB_DIM * HW) + hw0 + m;

    double lsum = 0.0;
    for (int c = c0; c < EMB_DIM; c += 2) {
      const float e  = er[c];
      const float zv = zb[(size_t)c * HW];
      const float diff = e - zv;       // fl(z_q - z)
      const float zq   = zv + diff;    // straight-through: fl(z + fl(z_q - z))
      ob[(size_t)c * HW] = zq;
      lsum += (double)diff * (double)diff;
    }
    double* red = (double*)&part[0][0];
    red[t] = lsum;
    __syncthreads();
    for (int s2 = 128; s2 > 0; s2 >>= 1) {
      if (t < s2) red[t] += red[t + s2];
      __syncthreads();
    }
    if (t == 0) {
      atomicAdd(loss_accum, red[0]);
      __threadfence();
      if (atomicAdd(&tickets[256], 1u) == 255u) {
        __threadfence();
        const double total = atomicAdd(loss_accum, 0.0);  // device-scope read
        const float L = (float)(total / (double)ZQ_ELEMS);
        out_loss[0] = __fadd_rn(L, __fmul_rn(0.25f, L));
      }
    }
  }
}

extern "C" void kernel_launch(void* const* d_in, const int* in_sizes, int n_in,
                              void* d_out, int out_size, void* d_ws, size_t ws_size,
                              hipStream_t stream) {
  const float* z   = (const float*)d_in[0];   // (32, 256, 32, 32) f32
  const float* emb = (const float*)d_in[1];   // (1024, 256) f32

  float* out       = (float*)d_out;           // z_q_out (B,C,H,W)
  float* out_loss  = out + ZQ_ELEMS;          // vq_loss scalar
  float* out_idx_f = out + ZQ_ELEMS + 1;      // encoding_indices as f32

  double* loss_accum = (double*)d_ws;
  float*  tnorm = (float*)((char*)d_ws + WS_TNORM);
  float*  snorm = (float*)((char*)d_ws + WS_SNORM);
  u64*    keys  = (u64*)((char*)d_ws + WS_KEYS);
  u32*    tickets = (u32*)((char*)d_ws + WS_TICK);
  u16*    EB    = (u16*)((char*)d_ws + WS_EB);

  vq_prep_kernel<<<132, 256, 0, stream>>>(z, emb, tnorm, snorm, keys, loss_accum,
                                          tickets, EB);
  vq_main_kernel<<<2048, 256, 0, stream>>>(z, emb, EB, tnorm, snorm, keys,
                                           loss_accum, tickets, out, out_idx_f,
                                           out_loss);
}

// Round 9
// 204.088 us; speedup vs baseline: 1.5522x; 1.5522x over previous
//
#include <hip/hip_runtime.h>

#define NUM_EMB 1024
#define EMB_DIM 256
#define NPIX    32768      // 32 * 32 * 32
#define HW      1024       // 32*32 spatial per batch
#define ZQ_ELEMS 8388608   // 32*256*32*32

// ws layout (bytes):
//   [0..8)                  double loss_accum
//   [8..8+4096)             float  tnorm[1024]
//   [8192..8192+131072)     float  snorm[32768]
//   [139264..+262144)       u64    keys[32768]  (argmin: (d_bits<<32)|idx)
//   [401408..+4)            u32    ticket counter
//   [401424..+3*524288)     u16    e-planes h/m/l [1024][256]
#define WS_TNORM 8
#define WS_SNORM 8192
#define WS_KEYS  139264
#define WS_CNT   401408
#define WS_EPL   401424
#define EPLANE_ELEMS (NUM_EMB * EMB_DIM)

typedef unsigned long long u64;
typedef unsigned int u32;
typedef unsigned short u16;

typedef __bf16 bf16x8 __attribute__((ext_vector_type(8)));
typedef float f32x16 __attribute__((ext_vector_type(16)));
typedef u16 u16x8 __attribute__((ext_vector_type(8)));

// ---- numpy pairwise_sum replica over 128 squared terms, stride between terms ----
__device__ __forceinline__ float pw128_sq(const float* x, int stride) {
  float r[8];
#pragma unroll
  for (int j = 0; j < 8; ++j) {
    float v = x[(size_t)j * stride];
    r[j] = __fmul_rn(v, v);
  }
  for (int i = 8; i < 128; i += 8) {
#pragma unroll
    for (int j = 0; j < 8; ++j) {
      float v = x[(size_t)(i + j) * stride];
      r[j] = __fadd_rn(r[j], __fmul_rn(v, v));
    }
  }
  float s01 = __fadd_rn(r[0], r[1]);
  float s23 = __fadd_rn(r[2], r[3]);
  float s45 = __fadd_rn(r[4], r[5]);
  float s67 = __fadd_rn(r[6], r[7]);
  return __fadd_rn(__fadd_rn(s01, s23), __fadd_rn(s45, s67));
}

// 3-way bf16 split: x = hf + mf + lf + eps, eps ~ 2^-26 |x|. Sterbenz-exact residuals.
__device__ __forceinline__ void split3(float x, u16& h, u16& m, u16& l) {
  u32 u = __float_as_uint(x);
  u16 hb = (u16)((u + 0x7fffu + ((u >> 16) & 1u)) >> 16);
  float hf = __uint_as_float((u32)hb << 16);
  float r1 = x - hf;                       // exact
  u32 u1 = __float_as_uint(r1);
  u16 mb = (u16)((u1 + 0x7fffu + ((u1 >> 16) & 1u)) >> 16);
  float mf = __uint_as_float((u32)mb << 16);
  float r2 = r1 - mf;                      // exact
  u32 u2 = __float_as_uint(r2);
  u16 lb = (u16)((u2 + 0x7fffu + ((u2 >> 16) & 1u)) >> 16);
  h = hb; m = mb; l = lb;
}

__device__ __forceinline__ u64 shfl_xor_u64(u64 v, int msk) {
  const u32 lo = __shfl_xor((u32)v, msk, 64);
  const u32 hi = __shfl_xor((u32)(v >> 32), msk, 64);
  return ((u64)hi << 32) | lo;
}

// ---- prep: keys=~0, loss=0, cnt=0, snorm (blk 0..127); tnorm + e-split (blk 128..131) ----
__global__ __launch_bounds__(256) void vq_prep_kernel(
    const float* __restrict__ z, const float* __restrict__ emb,
    float* __restrict__ tnorm, float* __restrict__ snorm,
    u64* __restrict__ keys, double* __restrict__ loss_accum,
    u32* __restrict__ counter,
    u16* __restrict__ eh, u16* __restrict__ em, u16* __restrict__ el) {
  const int gid = blockIdx.x * 256 + threadIdx.x;
  if (gid == 0) *loss_accum = 0.0;
  if (gid == 1) *counter = 0u;
  if (gid < NPIX) {
    keys[gid] = ~0ull;
    const int b = gid >> 10, hw = gid & 1023;
    const float* base = z + (size_t)b * (EMB_DIM * HW) + hw;
    snorm[gid] = __fadd_rn(pw128_sq(base, HW), pw128_sq(base + (size_t)128 * HW, HW));
  } else {
    const int k = gid - NPIX;
    if (k < NUM_EMB) {
      const float* row = emb + (size_t)k * EMB_DIM;
      tnorm[k] = __fadd_rn(pw128_sq(row, 1), pw128_sq(row + 128, 1));
      for (int c = 0; c < EMB_DIM; c += 8) {
        u16x8 vh, vm, vl;
#pragma unroll
        for (int j = 0; j < 8; ++j) {
          u16 h_, m_, l_;
          split3(row[c + j], h_, m_, l_);
          vh[j] = h_; vm[j] = m_; vl[j] = l_;
        }
        *(u16x8*)(eh + (size_t)k * EMB_DIM + c) = vh;
        *(u16x8*)(em + (size_t)k * EMB_DIM + c) = vm;
        *(u16x8*)(el + (size_t)k * EMB_DIM + c) = vl;
      }
    }
  }
}

// ---- main: 128 px x 128 codes per block, 32x32x16 MFMA, BOTH operands in LDS.
// 80B rows (measured conflict-free, R6) for zs AND es; 61.4 KB -> 2 blocks/CU;
// reg-prefetch one full compute phase ahead for both z (split on the fly) and e
// (pre-split planes).  Accumulation order bit-identical to validated R6/R7/R8.
// logical bid: pt = bid>>3, nt = bid&7; XCD swizzle: h -> (h&7)*256 + (h>>3)
__global__ __launch_bounds__(256, 2) void vq_main_kernel(
    const float* __restrict__ z,
    const u16* __restrict__ eh, const u16* __restrict__ em,
    const u16* __restrict__ el,
    const float* __restrict__ tnorm, const float* __restrict__ snorm,
    u64* __restrict__ keys) {
  __shared__ __align__(16) u16 zs[3][128][40];   // 30720 B
  __shared__ __align__(16) u16 es[3][128][40];   // 30720 B

  const int t   = threadIdx.x;
  const int hb  = blockIdx.x;
  const int bid = (hb & 7) * 256 + (hb >> 3);
  const int pt  = bid >> 3;
  const int ntb = bid & 7;
  const int m0  = pt * 128;
  const int n0  = ntb * 128;
  const int b   = m0 >> 10;
  const int hw0 = m0 & 1023;
  const float* zbase = z + (size_t)b * (EMB_DIM * HW) + hw0;

  const int l    = t & 63;
  const int wid  = t >> 6;
  const int wpx0 = (wid >> 1) * 64;   // wave pixel base within tile
  const int wcb  = (wid & 1) * 64;    // wave code base within tile
  const int cl   = l & 31;            // frag row/col lane
  const int hi   = l >> 5;            // k-octet select

  // staging: z — thread owns pixel sr, k-half skh (16 k's, two 16B chunks);
  //          e — thread owns code ecode, k-half ekh (two 16B chunks)
  const int sr    = t & 127;
  const int skh   = (t >> 7) * 16;
  const int ecode = t >> 1;
  const int ekh   = (t & 1) * 16;
  const u16* eplan[3] = {eh, em, el};
  const size_t ebase = (size_t)(n0 + ecode) * EMB_DIM + ekh;

  float gz[16];
  u16x8 ge[3][2];

  // prologue: load tile kt=0
#pragma unroll
  for (int j = 0; j < 16; ++j)
    gz[j] = zbase[(size_t)(skh + j) * HW + sr];
#pragma unroll
  for (int p = 0; p < 3; ++p) {
    ge[p][0] = *(const u16x8*)(eplan[p] + ebase);
    ge[p][1] = *(const u16x8*)(eplan[p] + ebase + 8);
  }

  f32x16 acc[2][2];
#pragma unroll
  for (int i = 0; i < 2; ++i)
#pragma unroll
    for (int j = 0; j < 2; ++j)
#pragma unroll
      for (int r = 0; r < 16; ++r) acc[i][j][r] = 0.0f;

  for (int kt = 0; kt < 8; ++kt) {
    // ---- split z + conflict-free b128 LDS writes; e written pre-split ----
#pragma unroll
    for (int c = 0; c < 2; ++c) {
      u16x8 vh, vm, vl;
#pragma unroll
      for (int j = 0; j < 8; ++j) {
        u16 h_, m_, l_;
        split3(gz[c * 8 + j], h_, m_, l_);
        vh[j] = h_; vm[j] = m_; vl[j] = l_;
      }
      *(u16x8*)&zs[0][sr][skh + c * 8] = vh;
      *(u16x8*)&zs[1][sr][skh + c * 8] = vm;
      *(u16x8*)&zs[2][sr][skh + c * 8] = vl;
    }
#pragma unroll
    for (int p = 0; p < 3; ++p) {
      *(u16x8*)&es[p][ecode][ekh]     = ge[p][0];
      *(u16x8*)&es[p][ecode][ekh + 8] = ge[p][1];
    }
    // ---- prefetch next tile (consumed after a full compute phase) ----
    if (kt < 7) {
      const int kb = (kt + 1) * 32;
#pragma unroll
      for (int j = 0; j < 16; ++j)
        gz[j] = zbase[(size_t)(kb + skh + j) * HW + sr];
#pragma unroll
      for (int p = 0; p < 3; ++p) {
        ge[p][0] = *(const u16x8*)(eplan[p] + ebase + kb);
        ge[p][1] = *(const u16x8*)(eplan[p] + ebase + kb + 8);
      }
    }
    __syncthreads();

#pragma unroll
    for (int ks = 0; ks < 2; ++ks) {
      bf16x8 af[3][2], bf[3][2];
#pragma unroll
      for (int p = 0; p < 3; ++p)
#pragma unroll
        for (int mt = 0; mt < 2; ++mt)
          af[p][mt] =
              *(const bf16x8*)&zs[p][wpx0 + mt * 32 + cl][ks * 16 + hi * 8];
#pragma unroll
      for (int p = 0; p < 3; ++p)
#pragma unroll
        for (int nn = 0; nn < 2; ++nn)
          bf[p][nn] =
              *(const bf16x8*)&es[p][wcb + nn * 32 + cl][ks * 16 + hi * 8];
      // 6 split-product planes: hh, hm, mh, mm, hl, lh
#define PROD(PA, PB)                                                          \
      _Pragma("unroll")                                                       \
      for (int mt = 0; mt < 2; ++mt) {                                        \
        _Pragma("unroll")                                                     \
        for (int nn = 0; nn < 2; ++nn)                                        \
          acc[mt][nn] = __builtin_amdgcn_mfma_f32_32x32x16_bf16(              \
              af[PA][mt], bf[PB][nn], acc[mt][nn], 0, 0, 0);                  \
      }
      PROD(0, 0)
      PROD(0, 1)
      PROD(1, 0)
      PROD(1, 1)
      PROD(0, 2)
      PROD(2, 0)
#undef PROD
    }
    __syncthreads();
  }

  // ---- epilogue: d = fl(fl(s+t) - 2m); argmin via u64 keys ----
  // C layout (validated R6-R8): col = cl (code), row = (reg&3)+8*(reg>>2)+4*hi
  const float tv0 = tnorm[n0 + wcb + cl];
  const float tv1 = tnorm[n0 + wcb + 32 + cl];
  u64 bk[2][16];
#pragma unroll
  for (int mt = 0; mt < 2; ++mt)
#pragma unroll
    for (int reg = 0; reg < 16; ++reg) {
      const int row = wpx0 + mt * 32 + (reg & 3) + 8 * (reg >> 2) + 4 * hi;
      const float s = snorm[m0 + row];
      const float d0 = __fsub_rn(__fadd_rn(s, tv0), 2.0f * acc[mt][0][reg]);
      const float d1 = __fsub_rn(__fadd_rn(s, tv1), 2.0f * acc[mt][1][reg]);
      const u64 k0 = ((u64)__float_as_uint(d0) << 32) | (u32)(n0 + wcb + cl);
      const u64 k1 =
          ((u64)__float_as_uint(d1) << 32) | (u32)(n0 + wcb + 32 + cl);
      bk[mt][reg] = k0 < k1 ? k0 : k1;
    }
  // reduce across the 32 cl-lanes (same rows, different codes)
#pragma unroll
  for (int off = 1; off < 32; off <<= 1) {
#pragma unroll
    for (int mt = 0; mt < 2; ++mt)
#pragma unroll
      for (int reg = 0; reg < 16; ++reg) {
        const u64 o = shfl_xor_u64(bk[mt][reg], off);
        if (o < bk[mt][reg]) bk[mt][reg] = o;
      }
  }

  // cross-wave combine via LDS (zs reusable after final barrier)
  u64* part = (u64*)&zs[0][0][0];   // [128][2]
  if (cl == 0) {
#pragma unroll
    for (int mt = 0; mt < 2; ++mt)
#pragma unroll
      for (int reg = 0; reg < 16; ++reg) {
        const int row = wpx0 + mt * 32 + (reg & 3) + 8 * (reg >> 2) + 4 * hi;
        part[row * 2 + (wid & 1)] = bk[mt][reg];
      }
  }
  __syncthreads();
  if (t < 128) {
    const u64 a = part[t * 2], c = part[t * 2 + 1];
    atomicMin(&keys[m0 + t], a < c ? a : c);
  }
}

// ---- outputs: z_q gather + straight-through + loss + idx; last block finalizes ----
__global__ __launch_bounds__(256) void vq_outputs_kernel(
    const float* __restrict__ z, const float* __restrict__ emb,
    const u64* __restrict__ keys, float* __restrict__ out,
    float* __restrict__ out_idx_f, double* __restrict__ loss_accum,
    u32* __restrict__ counter, float* __restrict__ out_loss) {
  const int t  = threadIdx.x;
  const int n0 = blockIdx.x * 64;
  const int m  = t & 63;
  const int c0 = t >> 6;
  const int b  = n0 >> 10;
  const int hw = n0 & 1023;
  const float* zb = z   + (size_t)b * (EMB_DIM * HW) + hw + m;
  float*       ob = out + (size_t)b * (EMB_DIM * HW) + hw + m;
  const int idx = (int)(u32)(keys[n0 + m] & 0xffffffffu);
  const float* er = emb + (size_t)idx * EMB_DIM;
  if (c0 == 0) out_idx_f[n0 + m] = (float)idx;

  double lsum = 0.0;
  for (int c = c0; c < EMB_DIM; c += 4) {
    const float e  = er[c];
    const float zv = zb[(size_t)c * HW];
    const float diff = e - zv;       // fl(z_q - z)
    const float zq   = zv + diff;    // straight-through: fl(z + fl(z_q - z))
    ob[(size_t)c * HW] = zq;
    lsum += (double)diff * (double)diff;
  }

  __shared__ double red[256];
  red[t] = lsum;
  __syncthreads();
  for (int s2 = 128; s2 > 0; s2 >>= 1) {
    if (t < s2) red[t] += red[t + s2];
    __syncthreads();
  }
  if (t == 0) {
    atomicAdd(loss_accum, red[0]);
    __threadfence();
    const u32 tick = atomicAdd(counter, 1u);
    if (tick == (u32)(NPIX / 64 - 1)) {
      const double total = atomicAdd(loss_accum, 0.0);  // device-scope read
      const float L = (float)(total / (double)ZQ_ELEMS);
      out_loss[0] = __fadd_rn(L, __fmul_rn(0.25f, L));
    }
  }
}

extern "C" void kernel_launch(void* const* d_in, const int* in_sizes, int n_in,
                              void* d_out, int out_size, void* d_ws, size_t ws_size,
                              hipStream_t stream) {
  const float* z   = (const float*)d_in[0];   // (32, 256, 32, 32) f32
  const float* emb = (const float*)d_in[1];   // (1024, 256) f32

  float* out       = (float*)d_out;           // z_q_out (B,C,H,W)
  float* out_loss  = out + ZQ_ELEMS;          // vq_loss scalar
  float* out_idx_f = out + ZQ_ELEMS + 1;      // encoding_indices as f32

  double* loss_accum = (double*)d_ws;
  float*  tnorm = (float*)((char*)d_ws + WS_TNORM);
  float*  snorm = (float*)((char*)d_ws + WS_SNORM);
  u64*    keys  = (u64*)((char*)d_ws + WS_KEYS);
  u32*    counter = (u32*)((char*)d_ws + WS_CNT);
  u16* eh = (u16*)((char*)d_ws + WS_EPL);
  u16* em = eh + EPLANE_ELEMS;
  u16* el = em + EPLANE_ELEMS;

  vq_prep_kernel<<<132, 256, 0, stream>>>(z, emb, tnorm, snorm, keys, loss_accum,
                                          counter, eh, em, el);
  vq_main_kernel<<<2048, 256, 0, stream>>>(z, eh, em, el, tnorm, snorm, keys);
  vq_outputs_kernel<<<NPIX / 64, 256, 0, stream>>>(z, emb, keys, out, out_idx_f,
                                                   loss_accum, counter, out_loss);
}